// Round 2
// baseline (1227.644 us; speedup 1.0000x reference)
//
#include <hip/hip_runtime.h>

#define KD    128
#define CDIM  256
#define VDIM  50000
#define BATCH 4
#define LMBDA_F 100.0f
#define TV    32
#define NCH   32
#define VC    1568   // 32 chunks, multiple of 32 (49 tiles of TV=32)

// ---------------------------------------------------------------------------
// GEMM: A[b,s](128 x 256) = E[b,s](128 x V) @ F[b,s](V x 256), split-K over
// 32 V-chunks, partials combined with atomicAdd (A zeroed by memset).
// Block: 256 threads (16x16), tile M=128 x N=128, register tile 8x8.
// ---------------------------------------------------------------------------
__global__ __launch_bounds__(256) void gemm_kernel(
    const float* __restrict__ feat_x, const float* __restrict__ feat_y,
    const float* __restrict__ Ex, const float* __restrict__ Ey,
    float* __restrict__ Ax, float* __restrict__ Ay)
{
  const int ch = blockIdx.x >> 1;   // 0..31 V-chunk
  const int nt = blockIdx.x & 1;    // 0..1 N-tile (c0 = nt*128)
  const int b  = blockIdx.y >> 1;   // 0..3
  const int s  = blockIdx.y & 1;    // 0: x side, 1: y side

  const float* E = (s ? Ey : Ex) + (size_t)b * KD * VDIM;
  const float* F = (s ? feat_y : feat_x) + (size_t)b * VDIM * CDIM;
  float* A = (s ? Ay : Ax) + (size_t)b * KD * CDIM;

  const int c0 = nt * 128;
  const int v0 = ch * VC;
  const int vend = min(VDIM, v0 + VC);

  __shared__ float El[TV][132];   // [vv][k], stride 132 (16B aligned, conflict-free reads)
  __shared__ float Fl[TV][132];   // [vv][c]

  const int t  = threadIdx.x;
  const int tx = t & 15, ty = t >> 4;

  float acc[8][8];
  #pragma unroll
  for (int i = 0; i < 8; ++i)
    #pragma unroll
    for (int j = 0; j < 8; ++j) acc[i][j] = 0.f;

  for (int vt = v0; vt < vend; vt += TV) {
    // stage E transposed: thread t loads 16 floats of row kk = t/2
    {
      const int kk = t >> 1, half = t & 1;
      const float* Erow = E + (size_t)kk * VDIM + vt;
      #pragma unroll
      for (int q = 0; q < 4; ++q) {
        const int vv = half * 16 + q * 4;
        float4 val = make_float4(0.f, 0.f, 0.f, 0.f);
        if (vt + vv < VDIM) val = *(const float4*)(Erow + vv);
        El[vv + 0][kk] = val.x; El[vv + 1][kk] = val.y;
        El[vv + 2][kk] = val.z; El[vv + 3][kk] = val.w;
      }
    }
    // stage F: thread t loads 4 float4 of row fv = t/8
    {
      const int fv = t >> 3, cq = t & 7;
      const float* Frow = F + (size_t)(vt + fv) * CDIM + c0;
      const bool ok = (vt + fv) < VDIM;
      #pragma unroll
      for (int q = 0; q < 4; ++q) {
        float4 val = make_float4(0.f, 0.f, 0.f, 0.f);
        if (ok) val = *(const float4*)(Frow + (cq + 8 * q) * 4);
        *(float4*)&Fl[fv][(cq + 8 * q) * 4] = val;
      }
    }
    __syncthreads();
    #pragma unroll 8
    for (int vv = 0; vv < TV; ++vv) {
      const float4 e0 = *(const float4*)&El[vv][ty * 8];
      const float4 e1 = *(const float4*)&El[vv][ty * 8 + 4];
      const float4 f0 = *(const float4*)&Fl[vv][tx * 8];
      const float4 f1 = *(const float4*)&Fl[vv][tx * 8 + 4];
      const float e[8] = {e0.x, e0.y, e0.z, e0.w, e1.x, e1.y, e1.z, e1.w};
      const float f[8] = {f0.x, f0.y, f0.z, f0.w, f1.x, f1.y, f1.z, f1.w};
      #pragma unroll
      for (int i2 = 0; i2 < 8; ++i2)
        #pragma unroll
        for (int j2 = 0; j2 < 8; ++j2)
          acc[i2][j2] = fmaf(e[i2], f[j2], acc[i2][j2]);
    }
    __syncthreads();
  }

  #pragma unroll
  for (int i2 = 0; i2 < 8; ++i2)
    #pragma unroll
    for (int j2 = 0; j2 < 8; ++j2)
      atomicAdd(&A[(ty * 8 + i2) * CDIM + c0 + tx * 8 + j2], acc[i2][j2]);
}

// ---------------------------------------------------------------------------
// AA_xx = A_x @ A_x^T, AA_yx = A_y @ A_x^T (per batch). 128x128, K=256.
// Grid (4 batches, 2 which, 4 c-chunks). A buffers are L2-resident (1 MB).
// ---------------------------------------------------------------------------
__global__ __launch_bounds__(256) void aa_kernel(
    const float* __restrict__ Ax, const float* __restrict__ Ay,
    float* __restrict__ AAxx, float* __restrict__ AAyx)
{
  const int b = blockIdx.x, which = blockIdx.y, cc = blockIdx.z;
  const float* L = (which ? Ay : Ax) + (size_t)b * KD * CDIM;
  const float* R = Ax + (size_t)b * KD * CDIM;
  float* O = (which ? AAyx : AAxx) + (size_t)b * KD * KD;

  const int t = threadIdx.x;
  const int tx = t & 15, ty = t >> 4;

  float acc[8][8];
  #pragma unroll
  for (int i = 0; i < 8; ++i)
    #pragma unroll
    for (int j = 0; j < 8; ++j) acc[i][j] = 0.f;

  for (int c = cc * 64; c < cc * 64 + 64; c += 4) {
    float4 l[8], r[8];
    #pragma unroll
    for (int i = 0; i < 8; ++i) l[i] = *(const float4*)(L + (ty * 8 + i) * CDIM + c);
    #pragma unroll
    for (int j = 0; j < 8; ++j) r[j] = *(const float4*)(R + (tx * 8 + j) * CDIM + c);
    #pragma unroll
    for (int i = 0; i < 8; ++i)
      #pragma unroll
      for (int j = 0; j < 8; ++j)
        acc[i][j] += l[i].x * r[j].x + l[i].y * r[j].y + l[i].z * r[j].z + l[i].w * r[j].w;
  }
  #pragma unroll
  for (int i = 0; i < 8; ++i)
    #pragma unroll
    for (int j = 0; j < 8; ++j)
      atomicAdd(&O[(ty * 8 + i) * KD + tx * 8 + j], acc[i][j]);
}

// ---------------------------------------------------------------------------
// MASK[b,i,j] from evals (tiny).
// ---------------------------------------------------------------------------
__global__ __launch_bounds__(256) void mask_kernel(
    const float* __restrict__ evals_x, const float* __restrict__ evals_y,
    float* __restrict__ MASKw)
{
  const int b = blockIdx.x;
  const int t = threadIdx.x;
  const float* ex = evals_x + b * KD;
  const float* ey = evals_y + b * KD;
  float s = 0.f;
  for (int k = 0; k < KD; ++k) { s = fmaxf(s, ex[k]); s = fmaxf(s, ey[k]); }
  const float inv_s = 1.0f / s;
  for (int idx = t; idx < KD * KD; idx += 256) {
    const int i = idx >> 7, j = idx & 127;
    const float g1 = sqrtf(ex[j] * inv_s);
    const float g2 = sqrtf(ey[i] * inv_s);
    const float d1 = 1.f / (g1 * g1 + 1.f);
    const float d2 = 1.f / (g2 * g2 + 1.f);
    const float re = g2 * d2 - g1 * d1;
    const float im = d2 - d1;
    MASKw[(size_t)b * KD * KD + idx] = re * re + im * im;
  }
}

// ---------------------------------------------------------------------------
// Solve: for (b,i): (AA_xx[b] + 100*diag(MASK[b,i,:])) x = AA_yx[b,i,:].
// One block per system, matrix in LDS (stride 132), GE without pivoting (SPD).
// ---------------------------------------------------------------------------
__global__ __launch_bounds__(256) void solve_kernel(
    const float* __restrict__ AAxx, const float* __restrict__ AAyx,
    const float* __restrict__ MASKw, float* __restrict__ out)
{
  const int b = blockIdx.x >> 7;
  const int i = blockIdx.x & 127;
  const int t = threadIdx.x;

  __shared__ float M[KD][132];
  __shared__ float fac[KD];
  __shared__ float rhs[KD];

  const float* S    = AAxx + (size_t)b * KD * KD;
  const float* mrow = MASKw + (size_t)b * KD * KD + i * KD;

  for (int idx4 = t; idx4 < KD * 32; idx4 += 256) {
    const int r = idx4 >> 5;
    const int c4 = (idx4 & 31) << 2;
    float4 v = *(const float4*)(S + r * KD + c4);
    if (r >= c4 && r < c4 + 4) (&v.x)[r - c4] += LMBDA_F * mrow[r];
    *(float4*)&M[r][c4] = v;
  }
  if (t < KD) rhs[t] = AAyx[(size_t)b * KD * KD + i * KD + t];
  __syncthreads();

  const int rowofs = t >> 5;
  const int lane = t & 31;

  // forward elimination
  for (int k = 0; k < KD - 1; ++k) {
    if (t > k && t < KD) {
      const float f = M[t][k] / M[k][k];
      fac[t] = f;
      rhs[t] -= f * rhs[k];
    }
    __syncthreads();
    const int c4 = ((k + 1) >> 2) + lane;
    if (c4 < 32) {
      const int cw = c4 << 2;
      const float4 mk = *(const float4*)&M[k][cw];
      for (int j = k + 1 + rowofs; j < KD; j += 8) {
        const float f = fac[j];
        float4 mj = *(float4*)&M[j][cw];
        mj.x -= f * mk.x; mj.y -= f * mk.y;
        mj.z -= f * mk.z; mj.w -= f * mk.w;
        *(float4*)&M[j][cw] = mj;
      }
    }
    __syncthreads();
  }

  // back substitution
  for (int k = KD - 1; k >= 0; --k) {
    const float xk = rhs[k] / M[k][k];
    __syncthreads();
    if (t == k) rhs[k] = xk;
    else if (t < k) rhs[t] -= M[t][k] * xk;
    __syncthreads();
  }

  if (t < KD) out[(size_t)blockIdx.x * KD + t] = rhs[t];
}

// ---------------------------------------------------------------------------
extern "C" void kernel_launch(void* const* d_in, const int* in_sizes, int n_in,
                              void* d_out, int out_size, void* d_ws, size_t ws_size,
                              hipStream_t stream) {
  const float* feat_x  = (const float*)d_in[0];
  const float* feat_y  = (const float*)d_in[1];
  const float* evals_x = (const float*)d_in[2];
  const float* evals_y = (const float*)d_in[3];
  const float* Etx     = (const float*)d_in[4];
  const float* Ety     = (const float*)d_in[5];
  float* out = (float*)d_out;

  float* ws    = (float*)d_ws;
  float* Ax    = ws;                       // 4*128*256 = 131072
  float* Ay    = Ax + BATCH * KD * CDIM;   // 131072
  float* AAxx  = Ay + BATCH * KD * CDIM;   // 4*128*128 = 65536
  float* AAyx  = AAxx + BATCH * KD * KD;   // 65536
  float* MASKw = AAyx + BATCH * KD * KD;   // 65536

  // zero the atomic-accumulated buffers (ws is poisoned to 0xAA each call)
  const size_t zero_bytes = (size_t)(2 * BATCH * KD * CDIM + 2 * BATCH * KD * KD) * sizeof(float);
  hipMemsetAsync(d_ws, 0, zero_bytes, stream);

  gemm_kernel<<<dim3(NCH * 2, BATCH * 2), 256, 0, stream>>>(feat_x, feat_y, Etx, Ety, Ax, Ay);
  aa_kernel<<<dim3(BATCH, 2, 4), 256, 0, stream>>>(Ax, Ay, AAxx, AAyx);
  mask_kernel<<<BATCH, 256, 0, stream>>>(evals_x, evals_y, MASKw);
  solve_kernel<<<BATCH * KD, 256, 0, stream>>>(AAxx, AAyx, MASKw, out);
}